// Round 7
// baseline (227.896 us; speedup 1.0000x reference)
//
#include <hip/hip_runtime.h>

#define BATCH 4096
#define D 128
#define SPLIT 4   // blocks per graph

typedef float floatx4 __attribute__((ext_vector_type(4)));

// ws layout (as int*):
// [0 .. 4096]          starts (4097 entries): starts[b] = first atom index of graph b
// [4100]               max_atoms
// [4101]               keep_count
// [4104 .. 4104+4096)  kept_to_orig mapping

// Streaming boundary detection: thread i covers the jump (mi[i-1] -> mi[i]);
// writes starts[b] for every graph id b in that jump range. dtype detection
// (int64 vs int32 in memory) is inlined: mi32[total-1] is the high word of a
// middle int64 element (==0) for int64, or the last sorted id (~4095, !=0)
// for int32 — a uniform broadcast load, effectively free.
__global__ __launch_bounds__(256) void starts_boundary_kernel(const int* __restrict__ mi,
                                                              int total, int* __restrict__ ws) {
    const int is64 = (mi[total - 1] == 0) ? 1 : 0;
    int i = blockIdx.x * blockDim.x + threadIdx.x;
    if (i >= total) return;
    int cur = is64 ? mi[(long long)i << 1] : mi[i];
    if (i == 0) {
        for (int b = 0; b <= cur; ++b) ws[b] = 0;
        return;
    }
    int prev = is64 ? mi[(long long)(i - 1) << 1] : mi[i - 1];
    for (int b = prev + 1; b <= cur; ++b) ws[b] = i;   // starts[b] = i for b in (prev, cur]
    if (i == total - 1) {
        for (int b = cur + 1; b <= BATCH; ++b) ws[b] = total;
    }
}

// 1024 threads = 16 waves; wave-level __shfl scan, 2 __syncthreads total.
__global__ __launch_bounds__(1024) void compute_meta_kernel(int* __restrict__ ws) {
    const int* starts = ws;
    int* kept = ws + 4104;
    const int tid = threadIdx.x;
    const int lane = tid & 63;
    const int w = tid >> 6;

    // each thread owns graphs [tid*4, tid*4+4)
    int4 s4 = *reinterpret_cast<const int4*>(&starts[tid * 4]);
    int s5 = starts[tid * 4 + 4];
    int cnt4[4] = { s4.y - s4.x, s4.z - s4.y, s4.w - s4.z, s5 - s4.w };

    int localmax = 0, localkeep = 0;
#pragma unroll
    for (int j = 0; j < 4; ++j) {
        localmax = max(localmax, cnt4[j]);
        localkeep += (cnt4[j] > 0) ? 1 : 0;
    }

    // wave-inclusive scan of localkeep + wave max
    int incl = localkeep;
#pragma unroll
    for (int off = 1; off < 64; off <<= 1) {
        int v = __shfl_up(incl, off, 64);
        if (lane >= off) incl += v;
    }
    int wmax = localmax;
#pragma unroll
    for (int off = 1; off < 64; off <<= 1) {
        wmax = max(wmax, __shfl_xor(wmax, off, 64));
    }

    __shared__ int wsum[16], wmaxs[16], wexcl[16];
    __shared__ int gmax_s, gsum_s;
    if (lane == 63) wsum[w] = incl;
    if (lane == 0)  wmaxs[w] = wmax;
    __syncthreads();

    if (w == 0) {
        int v = (lane < 16) ? wsum[lane] : 0;
        int m = (lane < 16) ? wmaxs[lane] : 0;
#pragma unroll
        for (int off = 1; off < 16; off <<= 1) {
            int u = __shfl_up(v, off, 64);
            if (lane >= off) v += u;
        }
#pragma unroll
        for (int off = 1; off < 16; off <<= 1) {
            m = max(m, __shfl_xor(m, off, 64));
        }
        if (lane < 16) wexcl[lane] = v - wsum[lane];
        if (lane == 15) gsum_s = v;
        if (lane == 0)  gmax_s = m;
    }
    __syncthreads();

    int o = wexcl[w] + (incl - localkeep);   // exclusive prefix for this thread
#pragma unroll
    for (int j = 0; j < 4; ++j) {
        if (cnt4[j] > 0) kept[o++] = tid * 4 + j;
    }
    if (tid == 0) { ws[4100] = gmax_s; ws[4101] = gsum_s; }
}

// One block per (kept-graph, chunk). Each block owns a CONTIGUOUS float4
// range of its graph's output block: linear address walk per block (DRAM
// page locality) instead of 16KB-strided interleave. Graph b's output is a
// contiguous memcpy of input rows [s, s+cnt) then a contiguous zero-fill.
// Nontemporal both sides: both streams are touch-once.
__global__ __launch_bounds__(256) void copy_graph_kernel(const floatx4* __restrict__ in4,
                                                         const int* __restrict__ ws,
                                                         floatx4* __restrict__ out4) {
    const int g = blockIdx.x / SPLIT;       // kept-graph index
    const int p = blockIdx.x - g * SPLIT;   // chunk within graph
    const int keep_count = ws[4101];
    if (g >= keep_count) return;

    const int b = ws[4104 + g];
    const int s = ws[b];
    const int cnt = ws[b + 1] - s;
    const int max_atoms = ws[4100];

    const floatx4* __restrict__ src = in4 + (s << 5);          // 32 float4 per row
    floatx4* __restrict__ dst = out4 + (g * max_atoms << 5);
    const int ncopy = cnt << 5;
    const int ntot = max_atoms << 5;

    // contiguous chunk [lo, hi) for this block, 256-aligned
    const int chunk = ((ntot + SPLIT - 1) / SPLIT + 255) & ~255;
    const int lo = p * chunk;
    const int hi = min(lo + chunk, ntot);
    const int mid = min(max(ncopy, lo), hi);   // copy/zero crossover clamped to [lo,hi)

    int i = lo + (int)threadIdx.x;
#pragma unroll 4
    for (; i < mid; i += 256) {
        __builtin_nontemporal_store(__builtin_nontemporal_load(&src[i]), &dst[i]);
    }
#pragma unroll 4
    for (; i < hi; i += 256) {
        __builtin_nontemporal_store((floatx4)(0.f), &dst[i]);
    }
}

extern "C" void kernel_launch(void* const* d_in, const int* in_sizes, int n_in,
                              void* d_out, int out_size, void* d_ws, size_t ws_size,
                              hipStream_t stream) {
    const float* feat = (const float*)d_in[0];
    const int* mi = (const int*)d_in[1];
    const int total = in_sizes[1];   // TOTAL atoms
    float* out = (float*)d_out;
    int* ws = (int*)d_ws;

    starts_boundary_kernel<<<(total + 255) / 256, 256, 0, stream>>>(mi, total, ws);
    compute_meta_kernel<<<1, 1024, 0, stream>>>(ws);
    copy_graph_kernel<<<BATCH * SPLIT, 256, 0, stream>>>((const floatx4*)feat, ws, (floatx4*)out);
}

// Round 8
// 217.303 us; speedup vs baseline: 1.0487x; 1.0487x over previous
//
#include <hip/hip_runtime.h>

#define BATCH 4096
#define D 128
#define SPLIT 4   // blocks per graph

typedef float floatx4 __attribute__((ext_vector_type(4)));

// ws layout (as int*):
// [0 .. 4096]          starts (4097 entries): starts[b] = first atom index of graph b
// [4100]               max_atoms
// [4101]               keep_count
// [4104 .. 4104+4096)  kept_to_orig mapping

// Streaming boundary detection: thread i covers the jump (mi[i-1] -> mi[i]);
// writes starts[b] for every graph id b in that jump range. dtype detection
// (int64 vs int32 in memory) is inlined: mi32[total-1] is the high word of a
// middle int64 element (==0) for int64, or the last sorted id (~4095, !=0)
// for int32 — a uniform broadcast load, effectively free.
__global__ __launch_bounds__(256) void starts_boundary_kernel(const int* __restrict__ mi,
                                                              int total, int* __restrict__ ws) {
    const int is64 = (mi[total - 1] == 0) ? 1 : 0;
    int i = blockIdx.x * blockDim.x + threadIdx.x;
    if (i >= total) return;
    int cur = is64 ? mi[(long long)i << 1] : mi[i];
    if (i == 0) {
        for (int b = 0; b <= cur; ++b) ws[b] = 0;
        return;
    }
    int prev = is64 ? mi[(long long)(i - 1) << 1] : mi[i - 1];
    for (int b = prev + 1; b <= cur; ++b) ws[b] = i;   // starts[b] = i for b in (prev, cur]
    if (i == total - 1) {
        for (int b = cur + 1; b <= BATCH; ++b) ws[b] = total;
    }
}

// 1024 threads = 16 waves; wave-level __shfl scan, 2 __syncthreads total.
__global__ __launch_bounds__(1024) void compute_meta_kernel(int* __restrict__ ws) {
    const int* starts = ws;
    int* kept = ws + 4104;
    const int tid = threadIdx.x;
    const int lane = tid & 63;
    const int w = tid >> 6;

    // each thread owns graphs [tid*4, tid*4+4)
    int4 s4 = *reinterpret_cast<const int4*>(&starts[tid * 4]);
    int s5 = starts[tid * 4 + 4];
    int cnt4[4] = { s4.y - s4.x, s4.z - s4.y, s4.w - s4.z, s5 - s4.w };

    int localmax = 0, localkeep = 0;
#pragma unroll
    for (int j = 0; j < 4; ++j) {
        localmax = max(localmax, cnt4[j]);
        localkeep += (cnt4[j] > 0) ? 1 : 0;
    }

    // wave-inclusive scan of localkeep + wave max
    int incl = localkeep;
#pragma unroll
    for (int off = 1; off < 64; off <<= 1) {
        int v = __shfl_up(incl, off, 64);
        if (lane >= off) incl += v;
    }
    int wmax = localmax;
#pragma unroll
    for (int off = 1; off < 64; off <<= 1) {
        wmax = max(wmax, __shfl_xor(wmax, off, 64));
    }

    __shared__ int wsum[16], wmaxs[16], wexcl[16];
    __shared__ int gmax_s, gsum_s;
    if (lane == 63) wsum[w] = incl;
    if (lane == 0)  wmaxs[w] = wmax;
    __syncthreads();

    if (w == 0) {
        int v = (lane < 16) ? wsum[lane] : 0;
        int m = (lane < 16) ? wmaxs[lane] : 0;
#pragma unroll
        for (int off = 1; off < 16; off <<= 1) {
            int u = __shfl_up(v, off, 64);
            if (lane >= off) v += u;
        }
#pragma unroll
        for (int off = 1; off < 16; off <<= 1) {
            m = max(m, __shfl_xor(m, off, 64));
        }
        if (lane < 16) wexcl[lane] = v - wsum[lane];
        if (lane == 15) gsum_s = v;
        if (lane == 0)  gmax_s = m;
    }
    __syncthreads();

    int o = wexcl[w] + (incl - localkeep);   // exclusive prefix for this thread
#pragma unroll
    for (int j = 0; j < 4; ++j) {
        if (cnt4[j] > 0) kept[o++] = tid * 4 + j;
    }
    if (tid == 0) { ws[4100] = gmax_s; ws[4101] = gsum_s; }
}

// One block per (kept-graph, quarter), 16KB-strided interleave (measured best
// vs contiguous per-block chunks in R7: 217.5 vs 227.9 µs). Graph b's output
// block is a contiguous memcpy of input rows [s, s+cnt) followed by a
// contiguous zero-fill — no per-iteration metadata, fully independent
// iterations. Nontemporal both sides: both streams are touch-once.
__global__ __launch_bounds__(256) void copy_graph_kernel(const floatx4* __restrict__ in4,
                                                         const int* __restrict__ ws,
                                                         floatx4* __restrict__ out4) {
    const int g = blockIdx.x / SPLIT;       // kept-graph index
    const int p = blockIdx.x - g * SPLIT;   // quarter
    const int keep_count = ws[4101];
    if (g >= keep_count) return;

    const int b = ws[4104 + g];
    const int s = ws[b];
    const int cnt = ws[b + 1] - s;
    const int max_atoms = ws[4100];

    const floatx4* __restrict__ src = in4 + (s << 5);          // 32 float4 per row
    floatx4* __restrict__ dst = out4 + (g * max_atoms << 5);
    const int ncopy = cnt << 5;
    const int ntot = max_atoms << 5;

    int i = threadIdx.x + (p << 8);         // start offset for this quarter
    const int stride = 256 * SPLIT;

#pragma unroll 4
    for (; i < ncopy; i += stride) {
        __builtin_nontemporal_store(__builtin_nontemporal_load(&src[i]), &dst[i]);
    }
#pragma unroll 4
    for (; i < ntot; i += stride) {
        __builtin_nontemporal_store((floatx4)(0.f), &dst[i]);
    }
}

extern "C" void kernel_launch(void* const* d_in, const int* in_sizes, int n_in,
                              void* d_out, int out_size, void* d_ws, size_t ws_size,
                              hipStream_t stream) {
    const float* feat = (const float*)d_in[0];
    const int* mi = (const int*)d_in[1];
    const int total = in_sizes[1];   // TOTAL atoms
    float* out = (float*)d_out;
    int* ws = (int*)d_ws;

    starts_boundary_kernel<<<(total + 255) / 256, 256, 0, stream>>>(mi, total, ws);
    compute_meta_kernel<<<1, 1024, 0, stream>>>(ws);
    copy_graph_kernel<<<BATCH * SPLIT, 256, 0, stream>>>((const floatx4*)feat, ws, (floatx4*)out);
}